// Round 1
// baseline (747.462 us; speedup 1.0000x reference)
//
#include <hip/hip_runtime.h>

typedef unsigned short u16;
typedef unsigned int u32;
typedef __attribute__((ext_vector_type(8))) short short8;
typedef __attribute__((ext_vector_type(4))) float f32x4;

__device__ inline float bf2f(u16 u) {
    u32 v = ((u32)u) << 16;
    return __builtin_bit_cast(float, v);
}
__device__ inline u16 f2bf(float f) {
    u32 u = __builtin_bit_cast(u32, f);
    u32 r = u + 0x7FFF + ((u >> 16) & 1);   // round-to-nearest-even
    return (u16)(r >> 16);
}
__device__ inline void unpack8(uint4 v, float* f) {
    u32 a[4] = {v.x, v.y, v.z, v.w};
#pragma unroll
    for (int i = 0; i < 4; ++i) {
        f[2 * i]     = bf2f((u16)(a[i] & 0xffff));
        f[2 * i + 1] = bf2f((u16)(a[i] >> 16));
    }
}

// ---------------- elementwise cast x -> bf16 ----------------
__global__ __launch_bounds__(256) void cast_f32_bf16(const float* __restrict__ in,
                                                     u16* __restrict__ out, int n) {
    int i = (blockIdx.x * 256 + threadIdx.x) * 4;
    if (i >= n) return;
    float4 v = *(const float4*)&in[i];
    ushort4 o;
    o.x = f2bf(v.x); o.y = f2bf(v.y); o.z = f2bf(v.z); o.w = f2bf(v.w);
    *(ushort4*)&out[i] = o;
}

// ---------------- transpose + cast weights: out[n][k] = bf16(in[k][n]) ----------------
__global__ __launch_bounds__(256) void transpose_cast(const float* __restrict__ in,
                                                      u16* __restrict__ out, int dim) {
    __shared__ float tile[32][33];
    const int n0 = blockIdx.x * 32, k0 = blockIdx.y * 32;
    const int tx = threadIdx.x & 31, ty = threadIdx.x >> 5;   // 32 x 8
#pragma unroll
    for (int i = 0; i < 32; i += 8)
        tile[ty + i][tx] = in[(size_t)(k0 + ty + i) * dim + n0 + tx];
    __syncthreads();
#pragma unroll
    for (int i = 0; i < 32; i += 8)
        out[(size_t)(n0 + ty + i) * dim + k0 + tx] = f2bf(tile[tx][ty + i]);
}

// ---------------- rope tables: cos/sin[pos][i], i in [0,64) ----------------
__global__ __launch_bounds__(256) void rope_tables(float* __restrict__ cosb,
                                                   float* __restrict__ sinb) {
    int idx = blockIdx.x * 256 + threadIdx.x;   // 2048*64
    int pos = idx >> 6, i = idx & 63;
    // inv_freq = 50000^(-i/64) = exp(-i * ln(50000)/64)
    float invf = __expf(-(float)i * (10.819778284410283f / 64.0f));
    float a = (float)pos * invf;
    cosb[idx] = cosf(a);
    sinb[idx] = sinf(a);
}

// ---------------- GEMM: C[M][N] = A[M][K] * Bt[N][K]^T, bf16 in, fp32 acc ----------------
template <bool BF16OUT>
__global__ __launch_bounds__(256) void gemm_bt(const u16* __restrict__ A,
                                               const u16* __restrict__ Bt,
                                               void* __restrict__ Cv,
                                               int M, int N, int K) {
    __shared__ u16 As[128][40];   // +8 pad: row stride 80B -> 2-way bank alias (free)
    __shared__ u16 Bs[128][40];
    const int bm = blockIdx.y, bn = blockIdx.x;
    const int tid = threadIdx.x;
    const int lane = tid & 63, w = tid >> 6;
    const int wm = (w >> 1) * 64, wn = (w & 1) * 64;
    const int lrow = lane & 15, lk8 = (lane >> 4) * 8;
    const int arow = tid >> 2, acol = (tid & 3) * 8;
    f32x4 acc[4][4] = {};

    for (int k0 = 0; k0 < K; k0 += 32) {
        uint4 a0 = *(const uint4*)&A[(size_t)(bm * 128 + arow) * K + k0 + acol];
        uint4 a1 = *(const uint4*)&A[(size_t)(bm * 128 + 64 + arow) * K + k0 + acol];
        uint4 b0 = *(const uint4*)&Bt[(size_t)(bn * 128 + arow) * K + k0 + acol];
        uint4 b1 = *(const uint4*)&Bt[(size_t)(bn * 128 + 64 + arow) * K + k0 + acol];
        __syncthreads();   // previous iteration's LDS reads complete
        *(uint4*)&As[arow][acol] = a0;
        *(uint4*)&As[64 + arow][acol] = a1;
        *(uint4*)&Bs[arow][acol] = b0;
        *(uint4*)&Bs[64 + arow][acol] = b1;
        __syncthreads();
        short8 af[4], bf_[4];
#pragma unroll
        for (int i = 0; i < 4; ++i) af[i] = *(const short8*)&As[wm + i * 16 + lrow][lk8];
#pragma unroll
        for (int j = 0; j < 4; ++j) bf_[j] = *(const short8*)&Bs[wn + j * 16 + lrow][lk8];
#pragma unroll
        for (int i = 0; i < 4; ++i)
#pragma unroll
            for (int j = 0; j < 4; ++j)
                acc[i][j] = __builtin_amdgcn_mfma_f32_16x16x32_bf16(af[i], bf_[j], acc[i][j], 0, 0, 0);
    }
    const int crow = (lane >> 4) * 4, ccol = lane & 15;
#pragma unroll
    for (int i = 0; i < 4; ++i)
#pragma unroll
        for (int j = 0; j < 4; ++j)
#pragma unroll
            for (int r = 0; r < 4; ++r) {
                size_t off = (size_t)(bm * 128 + wm + i * 16 + crow + r) * N +
                             (size_t)(bn * 128 + wn + j * 16 + ccol);
                if (BF16OUT) ((u16*)Cv)[off] = f2bf(acc[i][j][r]);
                else         ((float*)Cv)[off] = acc[i][j][r];
            }
}

// ---------------- RMSNorm(full 2048) + RoPE for q,k; writes [B,H,n,Dh] bf16 ----------------
__global__ __launch_bounds__(256) void norm_rope(const u16* __restrict__ qkv,   // [4096][6144]
                                                 const float* __restrict__ qw,
                                                 const float* __restrict__ kw,
                                                 const float* __restrict__ cosb,
                                                 const float* __restrict__ sinb,
                                                 u16* __restrict__ Qout,
                                                 u16* __restrict__ Kout) {
    __shared__ float qf[2048];
    __shared__ float kf[2048];
    __shared__ float red[8];
    const int r = blockIdx.x;               // token row
    const int b = r >> 11, pos = r & 2047;
    const int t = threadIdx.x;
    const u16* row = qkv + (size_t)r * 6144;
    uint4 qv = *(const uint4*)&row[t * 8];
    uint4 kv = *(const uint4*)&row[2048 + t * 8];
    float qe[8], ke[8];
    unpack8(qv, qe);
    unpack8(kv, ke);
    float sq = 0.f, sk = 0.f;
#pragma unroll
    for (int e = 0; e < 8; ++e) {
        qf[t * 8 + e] = qe[e];
        kf[t * 8 + e] = ke[e];
        sq += qe[e] * qe[e];
        sk += ke[e] * ke[e];
    }
#pragma unroll
    for (int msk = 1; msk < 64; msk <<= 1) {
        sq += __shfl_xor(sq, msk);
        sk += __shfl_xor(sk, msk);
    }
    if ((t & 63) == 0) { red[t >> 6] = sq; red[4 + (t >> 6)] = sk; }
    __syncthreads();
    float ssq = red[0] + red[1] + red[2] + red[3];
    float ssk = red[4] + red[5] + red[6] + red[7];
    // attention scale 1/sqrt(128) folded into q
    const float invq = 0.08838834764831845f / sqrtf(ssq * (1.f / 2048.f) + 1e-6f);
    const float invk = 1.0f / sqrtf(ssk * (1.f / 2048.f) + 1e-6f);
    const float* ct = cosb + pos * 64;
    const float* st = sinb + pos * 64;
    u16 qo[8], ko[8];
#pragma unroll
    for (int e = 0; e < 8; ++e) {
        int c = t * 8 + e;
        int jl = c & 127;          // index within head
        int hb = c & ~127;         // head base
        int jj = jl & 63;
        float cs = ct[jj], sn = st[jj];
        int pair = hb + ((jl < 64) ? jl + 64 : jl - 64);
        float sgn = (jl < 64) ? -1.f : 1.f;
        float xq = qf[c] * qw[c], pq = qf[pair] * qw[pair];
        float xk = kf[c] * kw[c], pk = kf[pair] * kw[pair];
        qo[e] = f2bf((xq * cs + sgn * pq * sn) * invq);
        ko[e] = f2bf((xk * cs + sgn * pk * sn) * invk);
    }
    const int h = (t * 8) >> 7;
    const int j0 = (t * 8) & 127;
    size_t o = ((size_t)(b * 16 + h) * 2048 + pos) * 128 + j0;
    *(uint4*)&Qout[o] = *(uint4*)qo;
    *(uint4*)&Kout[o] = *(uint4*)ko;
}

// ---------------- V transpose: Vt[bh][j][pos] = QKV[b*2048+pos][4096 + h*128 + j] ----------------
__global__ __launch_bounds__(256) void v_transpose(const u16* __restrict__ qkv,
                                                   u16* __restrict__ Vt) {
    __shared__ u16 tile[64][40];
    const int bxx = blockIdx.x;
    const int jt = bxx & 3, pt = (bxx >> 2) & 31, bh = bxx >> 7;
    const int b = bh >> 4, h = bh & 15;
    const int pos0 = pt * 64, j0 = jt * 32;
    const int t = threadIdx.x;
    {
        int p = t >> 2, jc = (t & 3) * 8;
        const u16* src = qkv + (size_t)(b * 2048 + pos0 + p) * 6144 + 4096 + h * 128 + j0 + jc;
        *(uint4*)&tile[p][jc] = *(const uint4*)src;
    }
    __syncthreads();
    {
        int j = t >> 3, pc = (t & 7) * 8;
        u16 tmp[8];
#pragma unroll
        for (int e = 0; e < 8; ++e) tmp[e] = tile[pc + e][j];
        *(uint4*)&Vt[((size_t)bh * 128 + j0 + j) * 2048 + pos0 + pc] = *(uint4*)tmp;
    }
}

// ---------------- causal flash attention, 1 wave per 16-row q-tile ----------------
__global__ __launch_bounds__(256) void attn_fwd(const u16* __restrict__ Qr,   // [bh][n][128]
                                                const u16* __restrict__ Kr,   // [bh][n][128]
                                                const u16* __restrict__ Vt,   // [bh][128][n]
                                                u16* __restrict__ O) {        // [4096][2048]
    __shared__ u16 pbuf[4][16][40];   // per-wave P tile (padded)
    const int bx = blockIdx.x;
    const int bh = bx >> 5, qb = bx & 31;
    const int tid = threadIdx.x;
    const int lane = tid & 63, w = tid >> 6;
    const int q0 = (qb * 4 + w) * 16;
    const int lrow = lane & 15, lk8 = (lane >> 4) * 8;
    const u16* Qh = Qr + (size_t)bh * 2048 * 128;
    const u16* Kh = Kr + (size_t)bh * 2048 * 128;
    const u16* Vh = Vt + (size_t)bh * 128 * 2048;

    short8 qa[4];
#pragma unroll
    for (int d = 0; d < 4; ++d)
        qa[d] = *(const short8*)&Qh[(q0 + lrow) * 128 + d * 32 + lk8];

    f32x4 acc[8] = {};
    float m[4] = {-3e38f, -3e38f, -3e38f, -3e38f};
    float l[4] = {0.f, 0.f, 0.f, 0.f};
    const int rbase = q0 + (lane >> 4) * 4;

    for (int k0 = 0; k0 < q0 + 16; k0 += 32) {
        f32x4 s[2] = {};
#pragma unroll
        for (int t2 = 0; t2 < 2; ++t2)
#pragma unroll
            for (int d = 0; d < 4; ++d) {
                short8 kb = *(const short8*)&Kh[(k0 + t2 * 16 + lrow) * 128 + d * 32 + lk8];
                s[t2] = __builtin_amdgcn_mfma_f32_16x16x32_bf16(qa[d], kb, s[t2], 0, 0, 0);
            }
        float corr[4], p0s[4], p1s[4];
        const int c0 = k0 + (lane & 15), c1 = c0 + 16;
#pragma unroll
        for (int r = 0; r < 4; ++r) {
            int rowg = rbase + r;
            float s0 = (c0 <= rowg) ? s[0][r] : -1e30f;
            float s1 = (c1 <= rowg) ? s[1][r] : -1e30f;
            float mx = fmaxf(s0, s1);
#pragma unroll
            for (int msk = 1; msk < 16; msk <<= 1) mx = fmaxf(mx, __shfl_xor(mx, msk));
            float mnew = fmaxf(m[r], mx);
            corr[r] = __expf(m[r] - mnew);
            float p0 = __expf(s0 - mnew);
            float p1 = __expf(s1 - mnew);
            float ps = p0 + p1;
#pragma unroll
            for (int msk = 1; msk < 16; msk <<= 1) ps += __shfl_xor(ps, msk);
            l[r] = l[r] * corr[r] + ps;
            m[r] = mnew;
            p0s[r] = p0;
            p1s[r] = p1;
        }
#pragma unroll
        for (int dt = 0; dt < 8; ++dt) {
            f32x4 tv = acc[dt];
            tv[0] *= corr[0]; tv[1] *= corr[1]; tv[2] *= corr[2]; tv[3] *= corr[3];
            acc[dt] = tv;
        }
#pragma unroll
        for (int r = 0; r < 4; ++r) {
            pbuf[w][(lane >> 4) * 4 + r][lane & 15] = f2bf(p0s[r]);
            pbuf[w][(lane >> 4) * 4 + r][16 + (lane & 15)] = f2bf(p1s[r]);
        }
        short8 pa = *(const short8*)&pbuf[w][lrow][lk8];   // same-wave LDS: in-order DS pipe
#pragma unroll
        for (int dt = 0; dt < 8; ++dt) {
            short8 vb = *(const short8*)&Vh[(dt * 16 + lrow) * 2048 + k0 + lk8];
            acc[dt] = __builtin_amdgcn_mfma_f32_16x16x32_bf16(pa, vb, acc[dt], 0, 0, 0);
        }
    }
#pragma unroll
    for (int r = 0; r < 4; ++r) {
        float inv = 1.0f / l[r];
        int rowg = rbase + r;
        size_t base = ((size_t)(bh >> 4) * 2048 + rowg) * 2048 + (size_t)(bh & 15) * 128;
#pragma unroll
        for (int dt = 0; dt < 8; ++dt)
            O[base + dt * 16 + (lane & 15)] = f2bf(acc[dt][r] * inv);
    }
}

extern "C" void kernel_launch(void* const* d_in, const int* in_sizes, int n_in,
                              void* d_out, int out_size, void* d_ws, size_t ws_size,
                              hipStream_t stream) {
    const float* x   = (const float*)d_in[0];
    const float* Wq  = (const float*)d_in[1];
    const float* Wk  = (const float*)d_in[2];
    const float* Wv  = (const float*)d_in[3];
    const float* Wo  = (const float*)d_in[4];
    const float* qnw = (const float*)d_in[5];
    const float* knw = (const float*)d_in[6];

    const size_t MB = 1ull << 20;
    char* ws = (char*)d_ws;
    u16* Xbf    = (u16*)(ws + 0);                 // 16 MB (reused as Qr after gemm1)
    u16* Qr     = (u16*)(ws + 0);
    u16* Wtqkv  = (u16*)(ws + 16 * MB);           // 24 MB
    u16* Wot    = (u16*)(ws + 40 * MB);           // 8 MB
    u16* QKV    = (u16*)(ws + 48 * MB);           // 48 MB (reused as attn_out)
    u16* AOut   = (u16*)(ws + 48 * MB);
    float* cosb = (float*)(ws + 96 * MB);         // 512 KB
    float* sinb = (float*)(ws + 96 * MB + 524288);// 512 KB
    u16* Kr     = (u16*)(ws + 97 * MB);           // 16 MB
    u16* Vt     = (u16*)(ws + 113 * MB);          // 16 MB (total 129 MB)

    // stage 0: conversions / tables (independent)
    cast_f32_bf16<<<8192, 256, 0, stream>>>(x, Xbf, 4096 * 2048);
    transpose_cast<<<dim3(64, 64), 256, 0, stream>>>(Wq, Wtqkv, 2048);
    transpose_cast<<<dim3(64, 64), 256, 0, stream>>>(Wk, Wtqkv + 2048 * 2048, 2048);
    transpose_cast<<<dim3(64, 64), 256, 0, stream>>>(Wv, Wtqkv + 2 * 2048 * 2048, 2048);
    transpose_cast<<<dim3(64, 64), 256, 0, stream>>>(Wo, Wot, 2048);
    rope_tables<<<512, 256, 0, stream>>>(cosb, sinb);

    // stage 1: fused QKV projection  [4096,2048] @ [2048,6144]
    gemm_bt<true><<<dim3(48, 32), 256, 0, stream>>>(Xbf, Wtqkv, (void*)QKV, 4096, 6144, 2048);

    // stage 2: RMSNorm + RoPE (q,k) and V transpose
    norm_rope<<<4096, 256, 0, stream>>>(QKV, qnw, knw, cosb, sinb, Qr, Kr);
    v_transpose<<<4096, 256, 0, stream>>>(QKV, Vt);

    // stage 3: causal flash attention
    attn_fwd<<<1024, 256, 0, stream>>>(Qr, Kr, Vt, AOut);

    // stage 4: output projection [4096,2048] @ [2048,2048] -> fp32 d_out
    gemm_bt<false><<<dim3(16, 32), 256, 0, stream>>>(AOut, Wot, d_out, 4096, 2048, 2048);
}

// Round 2
// 413.011 us; speedup vs baseline: 1.8098x; 1.8098x over previous
//
#include <hip/hip_runtime.h>

typedef unsigned short u16;
typedef unsigned int u32;
typedef __attribute__((ext_vector_type(8))) short short8;
typedef __attribute__((ext_vector_type(4))) float f32x4;

__device__ inline float bf2f(u16 u) {
    u32 v = ((u32)u) << 16;
    return __builtin_bit_cast(float, v);
}
__device__ inline u16 f2bf(float f) {
    u32 u = __builtin_bit_cast(u32, f);
    u32 r = u + 0x7FFF + ((u >> 16) & 1);   // round-to-nearest-even
    return (u16)(r >> 16);
}
__device__ inline void unpack8(uint4 v, float* f) {
    u32 a[4] = {v.x, v.y, v.z, v.w};
#pragma unroll
    for (int i = 0; i < 4; ++i) {
        f[2 * i]     = bf2f((u16)(a[i] & 0xffff));
        f[2 * i + 1] = bf2f((u16)(a[i] >> 16));
    }
}

// ---------------- elementwise cast x -> bf16 ----------------
__global__ __launch_bounds__(256) void cast_f32_bf16(const float* __restrict__ in,
                                                     u16* __restrict__ out, int n) {
    int i = (blockIdx.x * 256 + threadIdx.x) * 4;
    if (i >= n) return;
    float4 v = *(const float4*)&in[i];
    ushort4 o;
    o.x = f2bf(v.x); o.y = f2bf(v.y); o.z = f2bf(v.z); o.w = f2bf(v.w);
    *(ushort4*)&out[i] = o;
}

// ---------------- transpose + cast weights: out[n][k] = bf16(in[k][n]) ----------------
__global__ __launch_bounds__(256) void transpose_cast(const float* __restrict__ in,
                                                      u16* __restrict__ out, int dim) {
    __shared__ float tile[32][33];
    const int n0 = blockIdx.x * 32, k0 = blockIdx.y * 32;
    const int tx = threadIdx.x & 31, ty = threadIdx.x >> 5;   // 32 x 8
#pragma unroll
    for (int i = 0; i < 32; i += 8)
        tile[ty + i][tx] = in[(size_t)(k0 + ty + i) * dim + n0 + tx];
    __syncthreads();
#pragma unroll
    for (int i = 0; i < 32; i += 8)
        out[(size_t)(n0 + ty + i) * dim + k0 + tx] = f2bf(tile[tx][ty + i]);
}

// ---------------- rope tables: cos/sin[pos][i], i in [0,64) ----------------
__global__ __launch_bounds__(256) void rope_tables(float* __restrict__ cosb,
                                                   float* __restrict__ sinb) {
    int idx = blockIdx.x * 256 + threadIdx.x;   // 2048*64
    int pos = idx >> 6, i = idx & 63;
    float invf = __expf(-(float)i * (10.819778284410283f / 64.0f));
    float a = (float)pos * invf;
    cosb[idx] = cosf(a);
    sinb[idx] = sinf(a);
}

// ---------------- GEMM: C[M][N] = A[M][K] * Bt[N][K]^T, bf16 in, fp32 acc ----------------
template <bool BF16OUT>
__global__ __launch_bounds__(256) void gemm_bt(const u16* __restrict__ A,
                                               const u16* __restrict__ Bt,
                                               void* __restrict__ Cv,
                                               int M, int N, int K) {
    __shared__ u16 As[128][40];   // +8 pad: 2-way bank alias only (free)
    __shared__ u16 Bs[128][40];
    const int bm = blockIdx.y, bn = blockIdx.x;
    const int tid = threadIdx.x;
    const int lane = tid & 63, w = tid >> 6;
    const int wm = (w >> 1) * 64, wn = (w & 1) * 64;
    const int lrow = lane & 15, lk8 = (lane >> 4) * 8;
    const int arow = tid >> 2, acol = (tid & 3) * 8;
    f32x4 acc[4][4] = {};

    for (int k0 = 0; k0 < K; k0 += 32) {
        uint4 a0 = *(const uint4*)&A[(size_t)(bm * 128 + arow) * K + k0 + acol];
        uint4 a1 = *(const uint4*)&A[(size_t)(bm * 128 + 64 + arow) * K + k0 + acol];
        uint4 b0 = *(const uint4*)&Bt[(size_t)(bn * 128 + arow) * K + k0 + acol];
        uint4 b1 = *(const uint4*)&Bt[(size_t)(bn * 128 + 64 + arow) * K + k0 + acol];
        __syncthreads();
        *(uint4*)&As[arow][acol] = a0;
        *(uint4*)&As[64 + arow][acol] = a1;
        *(uint4*)&Bs[arow][acol] = b0;
        *(uint4*)&Bs[64 + arow][acol] = b1;
        __syncthreads();
        short8 af[4], bf_[4];
#pragma unroll
        for (int i = 0; i < 4; ++i) af[i] = *(const short8*)&As[wm + i * 16 + lrow][lk8];
#pragma unroll
        for (int j = 0; j < 4; ++j) bf_[j] = *(const short8*)&Bs[wn + j * 16 + lrow][lk8];
#pragma unroll
        for (int i = 0; i < 4; ++i)
#pragma unroll
            for (int j = 0; j < 4; ++j)
                acc[i][j] = __builtin_amdgcn_mfma_f32_16x16x32_bf16(af[i], bf_[j], acc[i][j], 0, 0, 0);
    }
    const int crow = (lane >> 4) * 4, ccol = lane & 15;
#pragma unroll
    for (int i = 0; i < 4; ++i)
#pragma unroll
        for (int j = 0; j < 4; ++j)
#pragma unroll
            for (int r = 0; r < 4; ++r) {
                size_t off = (size_t)(bm * 128 + wm + i * 16 + crow + r) * N +
                             (size_t)(bn * 128 + wn + j * 16 + ccol);
                if (BF16OUT) ((u16*)Cv)[off] = f2bf(acc[i][j][r]);
                else         ((float*)Cv)[off] = acc[i][j][r];
            }
}

// ---------------- RMSNorm(full 2048) + RoPE for q,k; writes [B,H,n,Dh] bf16 ----------------
__global__ __launch_bounds__(256) void norm_rope(const u16* __restrict__ qkv,   // [4096][6144]
                                                 const float* __restrict__ qw,
                                                 const float* __restrict__ kw,
                                                 const float* __restrict__ cosb,
                                                 const float* __restrict__ sinb,
                                                 u16* __restrict__ Qout,
                                                 u16* __restrict__ Kout) {
    __shared__ float qf[2048];
    __shared__ float kf[2048];
    __shared__ float red[8];
    const int r = blockIdx.x;               // token row
    const int b = r >> 11, pos = r & 2047;
    const int t = threadIdx.x;
    const u16* row = qkv + (size_t)r * 6144;
    uint4 qv = *(const uint4*)&row[t * 8];
    uint4 kv = *(const uint4*)&row[2048 + t * 8];
    float qe[8], ke[8];
    unpack8(qv, qe);
    unpack8(kv, ke);
    float sq = 0.f, sk = 0.f;
#pragma unroll
    for (int e = 0; e < 8; ++e) {
        qf[t * 8 + e] = qe[e];
        kf[t * 8 + e] = ke[e];
        sq += qe[e] * qe[e];
        sk += ke[e] * ke[e];
    }
#pragma unroll
    for (int msk = 1; msk < 64; msk <<= 1) {
        sq += __shfl_xor(sq, msk);
        sk += __shfl_xor(sk, msk);
    }
    if ((t & 63) == 0) { red[t >> 6] = sq; red[4 + (t >> 6)] = sk; }
    __syncthreads();
    float ssq = red[0] + red[1] + red[2] + red[3];
    float ssk = red[4] + red[5] + red[6] + red[7];
    const float invq = 0.08838834764831845f / sqrtf(ssq * (1.f / 2048.f) + 1e-6f);
    const float invk = 1.0f / sqrtf(ssk * (1.f / 2048.f) + 1e-6f);
    const float* ct = cosb + pos * 64;
    const float* st = sinb + pos * 64;
    u16 qo[8], ko[8];
#pragma unroll
    for (int e = 0; e < 8; ++e) {
        int c = t * 8 + e;
        int jl = c & 127;
        int hb = c & ~127;
        int jj = jl & 63;
        float cs = ct[jj], sn = st[jj];
        int pair = hb + ((jl < 64) ? jl + 64 : jl - 64);
        float sgn = (jl < 64) ? -1.f : 1.f;
        float xq = qf[c] * qw[c], pq = qf[pair] * qw[pair];
        float xk = kf[c] * kw[c], pk = kf[pair] * kw[pair];
        qo[e] = f2bf((xq * cs + sgn * pq * sn) * invq);
        ko[e] = f2bf((xk * cs + sgn * pk * sn) * invk);
    }
    const int h = (t * 8) >> 7;
    const int j0 = (t * 8) & 127;
    size_t o = ((size_t)(b * 16 + h) * 2048 + pos) * 128 + j0;
    *(uint4*)&Qout[o] = *(uint4*)qo;
    *(uint4*)&Kout[o] = *(uint4*)ko;
}

// ---------------- V transpose: Vt[bh][j][pos] = QKV[b*2048+pos][4096 + h*128 + j] ----------------
__global__ __launch_bounds__(256) void v_transpose(const u16* __restrict__ qkv,
                                                   u16* __restrict__ Vt) {
    __shared__ u16 tile[64][40];
    const int bxx = blockIdx.x;
    const int jt = bxx & 3, pt = (bxx >> 2) & 31, bh = bxx >> 7;
    const int b = bh >> 4, h = bh & 15;
    const int pos0 = pt * 64, j0 = jt * 32;
    const int t = threadIdx.x;
    {
        int p = t >> 2, jc = (t & 3) * 8;
        const u16* src = qkv + (size_t)(b * 2048 + pos0 + p) * 6144 + 4096 + h * 128 + j0 + jc;
        *(uint4*)&tile[p][jc] = *(const uint4*)src;
    }
    __syncthreads();
    {
        int j = t >> 3, pc = (t & 7) * 8;
        u16 tmp[8];
#pragma unroll
        for (int e = 0; e < 8; ++e) tmp[e] = tile[pc + e][j];
        *(uint4*)&Vt[((size_t)bh * 128 + j0 + j) * 2048 + pos0 + pc] = *(uint4*)tmp;
    }
}

// ---------------- causal flash attention v2 ----------------
// 4 waves/block, wave owns 16 q-rows, block tile = 64 rows, KV step = 64,
// block handles tile pair (pi, 31-pi) -> constant 33 KV-steps per block.
// K/V staged in LDS, shared by all 4 waves.
__global__ __launch_bounds__(256) void attn_fwd(const u16* __restrict__ Qr,   // [bh][n][128]
                                                const u16* __restrict__ Kr,   // [bh][n][128]
                                                const u16* __restrict__ Vt,   // [bh][128][n]
                                                u16* __restrict__ O) {        // [4096][2048]
    __shared__ u16 Ks[64][136];     // 272B row stride -> 2-way alias (free)
    __shared__ u16 Vs[128][72];     // 144B row stride -> 2-way alias
    __shared__ u16 Pb[4][16][72];   // per-wave P tile
    const int bx = blockIdx.x;       // 512 = 32 bh * 16 pairs
    const int bh = bx >> 4, pi = bx & 15;
    const int tid = threadIdx.x;
    const int lane = tid & 63, w = tid >> 6;
    const int lrow = lane & 15, lk8 = (lane >> 4) * 8;
    const u16* Qh = Qr + (size_t)bh * 2048 * 128;
    const u16* Kh = Kr + (size_t)bh * 2048 * 128;
    const u16* Vh = Vt + (size_t)bh * 128 * 2048;
    const int b = bh >> 4, h = bh & 15;

    for (int half = 0; half < 2; ++half) {
        const int qt = half ? (31 - pi) : pi;
        const int q0w = qt * 64 + w * 16;
        short8 qa[4];
#pragma unroll
        for (int d = 0; d < 4; ++d)
            qa[d] = *(const short8*)&Qh[(size_t)(q0w + lrow) * 128 + d * 32 + lk8];

        f32x4 acc[8] = {};
        float m[4] = {-3e38f, -3e38f, -3e38f, -3e38f};
        float l[4] = {0.f, 0.f, 0.f, 0.f};
        const int rbase = q0w + (lane >> 4) * 4;
        const int kend = qt * 64 + 64;

        for (int k0 = 0; k0 < kend; k0 += 64) {
            __syncthreads();   // previous step's LDS reads done
            // stage K tile [64][128]
#pragma unroll
            for (int rep = 0; rep < 4; ++rep) {
                int row = rep * 16 + (tid >> 4);
                int col = (tid & 15) * 8;
                *(uint4*)&Ks[row][col] = *(const uint4*)&Kh[(size_t)(k0 + row) * 128 + col];
            }
            // stage V tile [128][64]
#pragma unroll
            for (int rep = 0; rep < 4; ++rep) {
                int row = rep * 32 + (tid >> 3);
                int col = (tid & 7) * 8;
                *(uint4*)&Vs[row][col] = *(const uint4*)&Vh[(size_t)row * 2048 + k0 + col];
            }
            __syncthreads();

            // QK^T: S[16 rows][64 cols]
            f32x4 s[4] = {};
            __builtin_amdgcn_s_setprio(1);
#pragma unroll
            for (int j = 0; j < 4; ++j)
#pragma unroll
                for (int d = 0; d < 4; ++d) {
                    short8 kb = *(const short8*)&Ks[j * 16 + lrow][d * 32 + lk8];
                    s[j] = __builtin_amdgcn_mfma_f32_16x16x32_bf16(qa[d], kb, s[j], 0, 0, 0);
                }
            __builtin_amdgcn_s_setprio(0);

            const bool last = (k0 + 64 >= kend);
            float corr[4];
#pragma unroll
            for (int r = 0; r < 4; ++r) {
                const int rowg = rbase + r;
                float sv[4];
#pragma unroll
                for (int j = 0; j < 4; ++j) {
                    float xv = s[j][r];
                    if (last) {
                        int c = k0 + j * 16 + lrow;
                        xv = (c <= rowg) ? xv : -1e30f;
                    }
                    sv[j] = xv;
                }
                float mx = fmaxf(fmaxf(sv[0], sv[1]), fmaxf(sv[2], sv[3]));
#pragma unroll
                for (int msk = 1; msk < 16; msk <<= 1) mx = fmaxf(mx, __shfl_xor(mx, msk));
                float mnew = fmaxf(m[r], mx);
                corr[r] = __expf(m[r] - mnew);
                float p0 = __expf(sv[0] - mnew);
                float p1 = __expf(sv[1] - mnew);
                float p2 = __expf(sv[2] - mnew);
                float p3 = __expf(sv[3] - mnew);
                float ps = (p0 + p1) + (p2 + p3);
#pragma unroll
                for (int msk = 1; msk < 16; msk <<= 1) ps += __shfl_xor(ps, msk);
                l[r] = l[r] * corr[r] + ps;
                m[r] = mnew;
                const int prow = (lane >> 4) * 4 + r;
                Pb[w][prow][0 * 16 + lrow] = f2bf(p0);
                Pb[w][prow][1 * 16 + lrow] = f2bf(p1);
                Pb[w][prow][2 * 16 + lrow] = f2bf(p2);
                Pb[w][prow][3 * 16 + lrow] = f2bf(p3);
            }
#pragma unroll
            for (int dt = 0; dt < 8; ++dt) {
                f32x4 tv = acc[dt];
                tv[0] *= corr[0]; tv[1] *= corr[1]; tv[2] *= corr[2]; tv[3] *= corr[3];
                acc[dt] = tv;
            }
            // same-wave LDS round-trip (compiler inserts lgkmcnt)
            short8 pa0 = *(const short8*)&Pb[w][lrow][lk8];
            short8 pa1 = *(const short8*)&Pb[w][lrow][32 + lk8];
            __builtin_amdgcn_s_setprio(1);
#pragma unroll
            for (int dt = 0; dt < 8; ++dt) {
                short8 vb0 = *(const short8*)&Vs[dt * 16 + lrow][lk8];
                short8 vb1 = *(const short8*)&Vs[dt * 16 + lrow][32 + lk8];
                acc[dt] = __builtin_amdgcn_mfma_f32_16x16x32_bf16(pa0, vb0, acc[dt], 0, 0, 0);
                acc[dt] = __builtin_amdgcn_mfma_f32_16x16x32_bf16(pa1, vb1, acc[dt], 0, 0, 0);
            }
            __builtin_amdgcn_s_setprio(0);
        }

#pragma unroll
        for (int r = 0; r < 4; ++r) {
            float inv = 1.0f / l[r];
            int rowg = rbase + r;
            size_t base = ((size_t)b * 2048 + rowg) * 2048 + (size_t)h * 128;
#pragma unroll
            for (int dt = 0; dt < 8; ++dt)
                O[base + dt * 16 + (lane & 15)] = f2bf(acc[dt][r] * inv);
        }
    }
}

extern "C" void kernel_launch(void* const* d_in, const int* in_sizes, int n_in,
                              void* d_out, int out_size, void* d_ws, size_t ws_size,
                              hipStream_t stream) {
    const float* x   = (const float*)d_in[0];
    const float* Wq  = (const float*)d_in[1];
    const float* Wk  = (const float*)d_in[2];
    const float* Wv  = (const float*)d_in[3];
    const float* Wo  = (const float*)d_in[4];
    const float* qnw = (const float*)d_in[5];
    const float* knw = (const float*)d_in[6];

    const size_t MB = 1ull << 20;
    char* ws = (char*)d_ws;
    u16* Xbf    = (u16*)(ws + 0);                 // 16 MB (reused as Qr after gemm1)
    u16* Qr     = (u16*)(ws + 0);
    u16* Wtqkv  = (u16*)(ws + 16 * MB);           // 24 MB
    u16* Wot    = (u16*)(ws + 40 * MB);           // 8 MB
    u16* QKV    = (u16*)(ws + 48 * MB);           // 48 MB (reused as attn_out)
    u16* AOut   = (u16*)(ws + 48 * MB);
    float* cosb = (float*)(ws + 96 * MB);         // 512 KB
    float* sinb = (float*)(ws + 96 * MB + 524288);// 512 KB
    u16* Kr     = (u16*)(ws + 97 * MB);           // 16 MB
    u16* Vt     = (u16*)(ws + 113 * MB);          // 16 MB (total 129 MB)

    cast_f32_bf16<<<8192, 256, 0, stream>>>(x, Xbf, 4096 * 2048);
    transpose_cast<<<dim3(64, 64), 256, 0, stream>>>(Wq, Wtqkv, 2048);
    transpose_cast<<<dim3(64, 64), 256, 0, stream>>>(Wk, Wtqkv + 2048 * 2048, 2048);
    transpose_cast<<<dim3(64, 64), 256, 0, stream>>>(Wv, Wtqkv + 2 * 2048 * 2048, 2048);
    transpose_cast<<<dim3(64, 64), 256, 0, stream>>>(Wo, Wot, 2048);
    rope_tables<<<512, 256, 0, stream>>>(cosb, sinb);

    gemm_bt<true><<<dim3(48, 32), 256, 0, stream>>>(Xbf, Wtqkv, (void*)QKV, 4096, 6144, 2048);

    norm_rope<<<4096, 256, 0, stream>>>(QKV, qnw, knw, cosb, sinb, Qr, Kr);
    v_transpose<<<4096, 256, 0, stream>>>(QKV, Vt);

    attn_fwd<<<512, 256, 0, stream>>>(Qr, Kr, Vt, AOut);

    gemm_bt<false><<<dim3(16, 32), 256, 0, stream>>>(AOut, Wot, d_out, 4096, 2048, 2048);
}